// Round 5
// baseline (132.266 us; speedup 1.0000x reference)
//
#include <hip/hip_runtime.h>
#include <hip/hip_bf16.h>
#include <math.h>

#define N_NODES 8192
#define IN_FEAT 256
#define OUT_FEAT 128
#define WORDS_PER_ROW (N_NODES / 64)
#define CAPW 256
#define M_TILE 16

typedef unsigned long long u64;
typedef float v4f __attribute__((ext_vector_type(4)));
typedef short s8v __attribute__((ext_vector_type(8)));
typedef short s4v __attribute__((ext_vector_type(4)));

__device__ __forceinline__ float wred_sum_b(float v) {
    #pragma unroll
    for (int o = 32; o > 0; o >>= 1) v += __shfl_xor(v, o, 64);
    return v;
}
__device__ __forceinline__ float wred_max_b(float v) {
    #pragma unroll
    for (int o = 32; o > 0; o >>= 1) v = fmaxf(v, __shfl_xor(v, o, 64));
    return v;
}

// split f32 into bf16 hi (truncation) + bf16 lo (residual): ~16 mantissa bits
__device__ __forceinline__ void bsplit(float x, unsigned short& hi, unsigned short& lo) {
    unsigned int xb = __float_as_uint(x);
    hi = (unsigned short)(xb >> 16);
    float lof = x - __uint_as_float(xb & 0xFFFF0000u);
    lo = (unsigned short)(__float_as_uint(lof) >> 16);
}

// weight split, interleaved layout: wci[row*512 + (k>>3)*16 + (k&7)] = hi,
// [... + 8] = lo  -> each 8-k group is hi8|lo8 in 32 contiguous bytes.
__global__ __launch_bounds__(256) void prep_w(
    const float* __restrict__ Wc, const float* __restrict__ Ws,
    unsigned short* __restrict__ wci, unsigned short* __restrict__ wsi)
{
    int i = blockIdx.x * 256 + threadIdx.x;   // 0..32767
    int row = i >> 8, k = i & 255;
    int dst = row * 512 + ((k >> 3) << 4) + (k & 7);
    unsigned short h, l;
    bsplit(Wc[i], h, l); wci[dst] = h; wci[dst + 8] = l;
    bsplit(Ws[i], h, l); wsi[dst] = h; wsi[dst + 8] = l;
}

// 512 blocks x 256 threads. Edge-scatter preamble, then M-tile=16 bf16-split
// MFMA (two low-register-pressure passes) + the four GAT score vectors.
__global__ __launch_bounds__(256, 2) void node_feats(
    const float* __restrict__ hctx, const float* __restrict__ hstr,
    const unsigned short* __restrict__ wci, const unsigned short* __restrict__ wsi,
    const float* __restrict__ Wcb, const float* __restrict__ Wsb,
    const float* __restrict__ acw, const float* __restrict__ asw,
    const int* __restrict__ ei, int E, u64* __restrict__ bmp,
    float* __restrict__ hc,
    float* __restrict__ csrc, float* __restrict__ cdst,
    float* __restrict__ ssrc, float* __restrict__ sdst)
{
    __shared__ unsigned short aCh[M_TILE][264], aCl[M_TILE][264];   // +8 pad
    __shared__ unsigned short aSh[M_TILE][264], aSl[M_TILE][264];
    __shared__ float invsh[M_TILE];
    __shared__ float hcT[M_TILE][132];
    __shared__ float hsT[M_TILE][132];

    const int t = threadIdx.x;
    const int w = t >> 6, ln = t & 63;
    const int r0 = blockIdx.x * M_TILE;

    // --- phase 0: fused edge scatter (fire-and-forget atomics) ---
    {
        int pv = ei[2 * (ln & 31) + 1];
        u64 nz = __ballot(pv != 0);
        const int is64 = (nz == 0);
        for (int e = blockIdx.x * 256 + t; e < E; e += 512 * 256) {
            int s, d;
            if (is64) { s = ei[2 * e]; d = ei[2 * E + 2 * e]; }
            else      { s = ei[e];     d = ei[E + e]; }
            if ((unsigned)s < N_NODES && (unsigned)d < N_NODES)
                atomicOr(&bmp[(size_t)s * WORDS_PER_ROW + (d >> 6)], 1ull << (d & 63));
        }
    }

    // --- phase 1a: ctx -> bf16 hi/lo LDS ---
    #pragma unroll
    for (int j = 0; j < 4; j++) {
        int c = t + 256 * j;
        int r = c >> 6;
        int k = (c & 63) * 4;
        const float4 x = *(const float4*)(hctx + (size_t)(r0 + r) * IN_FEAT + k);
        unsigned short h0, h1, h2, h3, l0, l1, l2, l3;
        bsplit(x.x, h0, l0); bsplit(x.y, h1, l1);
        bsplit(x.z, h2, l2); bsplit(x.w, h3, l3);
        s4v hv = { (short)h0, (short)h1, (short)h2, (short)h3 };
        s4v lv = { (short)l0, (short)l1, (short)l2, (short)l3 };
        *(s4v*)&aCh[r][k] = hv;
        *(s4v*)&aCl[r][k] = lv;
    }

    // --- phase 1b: structure softmax (wave w owns rows 4w..4w+3) ---
    #pragma unroll
    for (int rr = 0; rr < 4; rr++) {
        int r = w * 4 + rr;
        const float* srow = hstr + (size_t)(r0 + r) * IN_FEAT;
        float x0 = srow[ln], x1 = srow[ln + 64], x2 = srow[ln + 128], x3 = srow[ln + 192];
        float mx = wred_max_b(fmaxf(fmaxf(x0, x1), fmaxf(x2, x3)));
        float e0 = __expf(x0 - mx), e1 = __expf(x1 - mx);
        float e2 = __expf(x2 - mx), e3 = __expf(x3 - mx);
        float s = wred_sum_b(e0 + e1 + e2 + e3);
        if (ln == 0) invsh[r] = 1.0f / s;
        unsigned short h, l;
        bsplit(e0, h, l); aSh[r][ln]       = h; aSl[r][ln]       = l;
        bsplit(e1, h, l); aSh[r][ln + 64]  = h; aSl[r][ln + 64]  = l;
        bsplit(e2, h, l); aSh[r][ln + 128] = h; aSl[r][ln + 128] = l;
        bsplit(e3, h, l); aSh[r][ln + 192] = h; aSl[r][ln + 192] = l;
    }
    __syncthreads();

    // --- phase 2: MFMA, two passes to keep VGPR pressure low ---
    const int m = ln & 15, q = ln >> 4;
    const int nA = (w << 5) + m, nB = nA + 16;

    v4f aC0 = {0.f,0.f,0.f,0.f}, aC1 = {0.f,0.f,0.f,0.f};
    v4f aS0 = {0.f,0.f,0.f,0.f}, aS1 = {0.f,0.f,0.f,0.f};

    {   // pass 1: context
        const unsigned short* p0 = wci + nA * 512;
        const unsigned short* p1 = wci + nB * 512;
        #pragma unroll 2
        for (int ks = 0; ks < 8; ks++) {
            const int ko = ks * 32 + q * 8;
            const int io = 2 * ko;
            s8v ah  = *(const s8v*)&aCh[m][ko];
            s8v al  = *(const s8v*)&aCl[m][ko];
            s8v b0h = *(const s8v*)(p0 + io);
            s8v b0l = *(const s8v*)(p0 + io + 8);
            s8v b1h = *(const s8v*)(p1 + io);
            s8v b1l = *(const s8v*)(p1 + io + 8);
            aC0 = __builtin_amdgcn_mfma_f32_16x16x32_bf16(al, b0h, aC0, 0, 0, 0);
            aC0 = __builtin_amdgcn_mfma_f32_16x16x32_bf16(ah, b0l, aC0, 0, 0, 0);
            aC0 = __builtin_amdgcn_mfma_f32_16x16x32_bf16(ah, b0h, aC0, 0, 0, 0);
            aC1 = __builtin_amdgcn_mfma_f32_16x16x32_bf16(al, b1h, aC1, 0, 0, 0);
            aC1 = __builtin_amdgcn_mfma_f32_16x16x32_bf16(ah, b1l, aC1, 0, 0, 0);
            aC1 = __builtin_amdgcn_mfma_f32_16x16x32_bf16(ah, b1h, aC1, 0, 0, 0);
        }
    }
    {   // pass 2: structure
        const unsigned short* p0 = wsi + nA * 512;
        const unsigned short* p1 = wsi + nB * 512;
        #pragma unroll 2
        for (int ks = 0; ks < 8; ks++) {
            const int ko = ks * 32 + q * 8;
            const int io = 2 * ko;
            s8v ah  = *(const s8v*)&aSh[m][ko];
            s8v al  = *(const s8v*)&aSl[m][ko];
            s8v b0h = *(const s8v*)(p0 + io);
            s8v b0l = *(const s8v*)(p0 + io + 8);
            s8v b1h = *(const s8v*)(p1 + io);
            s8v b1l = *(const s8v*)(p1 + io + 8);
            aS0 = __builtin_amdgcn_mfma_f32_16x16x32_bf16(al, b0h, aS0, 0, 0, 0);
            aS0 = __builtin_amdgcn_mfma_f32_16x16x32_bf16(ah, b0l, aS0, 0, 0, 0);
            aS0 = __builtin_amdgcn_mfma_f32_16x16x32_bf16(ah, b0h, aS0, 0, 0, 0);
            aS1 = __builtin_amdgcn_mfma_f32_16x16x32_bf16(al, b1h, aS1, 0, 0, 0);
            aS1 = __builtin_amdgcn_mfma_f32_16x16x32_bf16(ah, b1l, aS1, 0, 0, 0);
            aS1 = __builtin_amdgcn_mfma_f32_16x16x32_bf16(ah, b1h, aS1, 0, 0, 0);
        }
    }

    // --- epilogue: C-layout (col=lane&15, row=quad*4+reg) -> LDS tiles ---
    const float cbA = Wcb[nA], cbB = Wcb[nB];
    const float sbA = Wsb[nA], sbB = Wsb[nB];
    #pragma unroll
    for (int p = 0; p < 4; p++) {
        int row = q * 4 + p;
        float iv = invsh[row];
        hcT[row][nA] = aC0[p] + cbA;
        hcT[row][nB] = aC1[p] + cbB;
        hsT[row][nA] = aS0[p] * iv + sbA;
        hsT[row][nB] = aS1[p] * iv + sbB;
    }
    __syncthreads();

    #pragma unroll
    for (int j = 0; j < 8; j++) {
        int f = t + 256 * j;
        int r = f >> 7, c = f & 127;
        hc[(size_t)(r0 + r) * OUT_FEAT + c] = hcT[r][c];
    }

    float a0 = acw[ln], a0b = acw[ln + 64], a1 = acw[128 + ln], a1b = acw[192 + ln];
    float b0 = asw[ln], b0b = asw[ln + 64], b1 = asw[128 + ln], b1b = asw[192 + ln];
    #pragma unroll
    for (int rr = 0; rr < 4; rr++) {
        int r = w + rr * 4;
        float c0 = hcT[r][ln], c1 = hcT[r][ln + 64];
        float s0 = hsT[r][ln], s1 = hsT[r][ln + 64];
        float v0 = wred_sum_b(c0 * a0 + c1 * a0b);
        float v1 = wred_sum_b(c0 * a1 + c1 * a1b);
        float v2 = wred_sum_b(s0 * b0 + s1 * b0b);
        float v3 = wred_sum_b(s0 * b1 + s1 * b1b);
        if (ln == 0) {
            csrc[r0 + r] = v0; cdst[r0 + r] = v1;
            ssrc[r0 + r] = v2; sdst[r0 + r] = v3;
        }
    }
}

// One WAVE per row: 2048 blocks x 256 threads (4 rows/block). No block barriers.
__global__ __launch_bounds__(256) void attn(
    const u64* __restrict__ bmp,
    const float* __restrict__ hc,
    const float* __restrict__ csrc, const float* __restrict__ cdst,
    const float* __restrict__ ssrc, const float* __restrict__ sdst,
    const float* __restrict__ wscoff, const float* __restrict__ wccoff,
    float* __restrict__ out)
{
    __shared__ int   jl[4][CAPW];
    __shared__ float pl[4][CAPW];

    const int w  = threadIdx.x >> 6;
    const int ln = threadIdx.x & 63;
    const int i  = blockIdx.x * 4 + w;

    const float wS = fabsf(wscoff[0]);
    const float wC = fabsf(wccoff[0]);
    const float cs = csrc[i], ss = ssrc[i];

    ulonglong2 wv = *(const ulonglong2*)(bmp + (size_t)i * WORDS_PER_ROW + 2 * ln);
    int c = __popcll(wv.x) + __popcll(wv.y);

    int inc = c;
    #pragma unroll
    for (int o = 1; o < 64; o <<= 1) {
        int y = __shfl_up(inc, o, 64);
        if (ln >= o) inc += y;
    }
    int pre = inc - c;
    int cnt = __shfl(inc, 63, 64);

    int idx = pre;
    #pragma unroll
    for (int h = 0; h < 2; h++) {
        u64 ww = (h == 0) ? wv.x : wv.y;
        int jb = ln * 128 + h * 64;
        while (ww) {
            int b = __ffsll(ww) - 1; ww &= ww - 1;
            int j = jb + b;
            float ac  = cs + cdst[j];
            float as_ = ss + sdst[j];
            ac  = (ac  > 0.0f) ? ac  : 0.01f * ac;
            as_ = (as_ > 0.0f) ? as_ : 0.01f * as_;
            if (idx < CAPW) { jl[w][idx] = j; pl[w][idx] = wS * ac + wC * as_; }
            idx++;
        }
    }
    if (cnt > CAPW) cnt = CAPW;
    __threadfence_block();

    if (cnt == 0) {
        float2 acc = {0.f, 0.f};
        const float2* hc2 = (const float2*)hc;
        for (int j = 0; j < N_NODES; j++) {
            float2 h2 = hc2[(size_t)j * 64 + ln];
            acc.x += h2.x; acc.y += h2.y;
        }
        float2 o2 = { acc.x / (float)N_NODES, acc.y / (float)N_NODES };
        *(float2*)(out + (size_t)i * OUT_FEAT + 2 * ln) = o2;
        return;
    }

    float m = -1e30f;
    for (int k = ln; k < cnt; k += 64) m = fmaxf(m, pl[w][k]);
    m = wred_max_b(m);
    float s = 0.0f;
    for (int k = ln; k < cnt; k += 64) {
        float p = __expf(pl[w][k] - m);
        pl[w][k] = p;
        s += p;
    }
    s = wred_sum_b(s);
    float inv = 1.0f / s;
    __threadfence_block();

    const float2* hc2 = (const float2*)hc;
    float2 acc = {0.f, 0.f};
    int k = 0;
    for (; k + 4 <= cnt; k += 4) {
        int   j0 = jl[w][k],   j1 = jl[w][k+1], j2 = jl[w][k+2], j3 = jl[w][k+3];
        float p0 = pl[w][k],   p1 = pl[w][k+1], p2 = pl[w][k+2], p3 = pl[w][k+3];
        float2 h0 = hc2[(size_t)j0 * 64 + ln];
        float2 h1 = hc2[(size_t)j1 * 64 + ln];
        float2 h2 = hc2[(size_t)j2 * 64 + ln];
        float2 h3 = hc2[(size_t)j3 * 64 + ln];
        acc.x += p0 * h0.x + p1 * h1.x + p2 * h2.x + p3 * h3.x;
        acc.y += p0 * h0.y + p1 * h1.y + p2 * h2.y + p3 * h3.y;
    }
    for (; k < cnt; k++) {
        float2 h0 = hc2[(size_t)jl[w][k] * 64 + ln];
        float p0 = pl[w][k];
        acc.x += p0 * h0.x; acc.y += p0 * h0.y;
    }
    float2 o2 = { acc.x * inv, acc.y * inv };
    *(float2*)(out + (size_t)i * OUT_FEAT + 2 * ln) = o2;
}

extern "C" void kernel_launch(void* const* d_in, const int* in_sizes, int n_in,
                              void* d_out, int out_size, void* d_ws, size_t ws_size,
                              hipStream_t stream)
{
    const float* hctx = (const float*)d_in[0];
    const float* hstr = (const float*)d_in[1];
    const int*   ei   = (const int*)d_in[2];
    const float* Wc   = (const float*)d_in[3];
    const float* Wcb  = (const float*)d_in[4];
    const float* Ws   = (const float*)d_in[5];
    const float* Wsb  = (const float*)d_in[6];
    const float* acw  = (const float*)d_in[7];
    const float* asw  = (const float*)d_in[8];
    const float* wsco = (const float*)d_in[9];
    const float* wcco = (const float*)d_in[10];
    float* out = (float*)d_out;

    const int n2 = in_sizes[2];
    const int E  = (n2 == 4 * 262144) ? 262144 : n2 / 2;

    char* ws = (char*)d_ws;
    size_t off = 0;
    float* hc   = (float*)(ws + off); off += (size_t)N_NODES * OUT_FEAT * sizeof(float);
    float* csrc = (float*)(ws + off); off += (size_t)N_NODES * sizeof(float);
    float* cdst = (float*)(ws + off); off += (size_t)N_NODES * sizeof(float);
    float* ssrc = (float*)(ws + off); off += (size_t)N_NODES * sizeof(float);
    float* sdst = (float*)(ws + off); off += (size_t)N_NODES * sizeof(float);
    off = (off + 255) & ~(size_t)255;
    u64* bmp    = (u64*)(ws + off);   off += (size_t)N_NODES * WORDS_PER_ROW * sizeof(u64);
    unsigned short* wci = (unsigned short*)(ws + off); off += (size_t)OUT_FEAT * IN_FEAT * 2 * sizeof(unsigned short);
    unsigned short* wsi = (unsigned short*)(ws + off); off += (size_t)OUT_FEAT * IN_FEAT * 2 * sizeof(unsigned short);

    hipMemsetAsync(bmp, 0, (size_t)N_NODES * WORDS_PER_ROW * sizeof(u64), stream);

    prep_w<<<128, 256, 0, stream>>>(Wc, Ws, wci, wsi);
    node_feats<<<N_NODES / M_TILE, 256, 0, stream>>>(hctx, hstr, wci, wsi,
                                                     Wcb, Wsb, acw, asw, ei, E, bmp,
                                                     hc, csrc, cdst, ssrc, sdst);
    attn<<<N_NODES / 4, 256, 0, stream>>>(bmp, hc, csrc, cdst, ssrc, sdst, wsco, wcco, out);
}